// Round 12
// baseline (318.231 us; speedup 1.0000x reference)
//
#include <hip/hip_runtime.h>
#include <hip/hip_bf16.h>

#define NN 50000
#define NE 600000
#define DD 128
#define NR 8
#define NB (NN * NR)                   // 400000 (dst,rel) bins
#define NCHUNK8 ((NB + 255) / 256)     // 1563 scan blocks
#define PERT ((NCHUNK8 + 255) / 256)   // 7 items/thread in bscan

typedef __attribute__((ext_vector_type(8))) short bf16x8;
typedef __attribute__((ext_vector_type(4))) float f32x4;

__device__ __forceinline__ unsigned short f2bf(float f) {
  __hip_bfloat16 h = __float2bfloat16(f);
  return *reinterpret_cast<unsigned short*>(&h);
}
__device__ __forceinline__ unsigned pk2(float lo, float hi) {
  return (unsigned)f2bf(lo) | ((unsigned)f2bf(hi) << 16);
}
__device__ __forceinline__ float bflo(unsigned u) { return __uint_as_float(u << 16); }
__device__ __forceinline__ float bfhi(unsigned u) { return __uint_as_float(u & 0xffff0000u); }

// ---------------- weight transpose+convert: WT[m][o][d] = bf16(W[m][d][o]) ----------------
__global__ __launch_bounds__(128) void convw_kernel(
    const float* __restrict__ W1, const float* __restrict__ Ws1,
    const float* __restrict__ W2, const float* __restrict__ Ws2,
    unsigned short* __restrict__ WT)
{
  const int m = blockIdx.y, o = blockIdx.x, d = threadIdx.x;
  const float* src;
  if (m < 8)       src = W1 + (size_t)m * DD * DD;
  else if (m == 8) src = Ws1;
  else if (m < 17) src = W2 + (size_t)(m - 9) * DD * DD;
  else             src = Ws2;
  WT[(size_t)m * DD * DD + o * DD + d] = f2bf(src[(size_t)d * DD + o]);
}

// ---------------- h0 = bf16(emb[node_ids]) ----------------
__global__ __launch_bounds__(256) void convh_kernel(
    const float* __restrict__ emb, const int* __restrict__ ids,
    unsigned short* __restrict__ h)
{
  const int gid = blockIdx.x * 256 + threadIdx.x;   // NN*16 total
  if (gid >= NN * 16) return;
  const int row = gid >> 4;
  const int off = (gid & 15) * 8;
  const int srcRow = ids[row];
  const float* src = emb + (size_t)srcRow * DD + off;
  const float4 a = *reinterpret_cast<const float4*>(src);
  const float4 b = *reinterpret_cast<const float4*>(src + 4);
  uint4 u;
  u.x = pk2(a.x, a.y); u.y = pk2(a.z, a.w);
  u.z = pk2(b.x, b.y); u.w = pk2(b.z, b.w);
  *reinterpret_cast<uint4*>(h + (size_t)row * DD + off) = u;
}

// ---------------- CSR build over (dst,rel) bins ----------------
__global__ __launch_bounds__(256) void hist_kernel(
    const int* __restrict__ dst, const int* __restrict__ et,
    int* __restrict__ deg)
{
  const int e = blockIdx.x * 256 + threadIdx.x;
  if (e < NE) atomicAdd(&deg[dst[e] * NR + et[e]], 1);
}

__global__ __launch_bounds__(256) void bsum_kernel(
    const int* __restrict__ deg, int* __restrict__ bsum)
{
  __shared__ int tmp[256];
  const int t = threadIdx.x;
  const int i = blockIdx.x * 256 + t;
  tmp[t] = (i < NB) ? deg[i] : 0;
  __syncthreads();
#pragma unroll
  for (int off = 128; off > 0; off >>= 1) {
    if (t < off) tmp[t] += tmp[t + off];
    __syncthreads();
  }
  if (t == 0) bsum[blockIdx.x] = tmp[0];
}

// 1 block: exclusive scan of bsum[NCHUNK8] -> bbase[NCHUNK8]; 7 items/thread
__global__ __launch_bounds__(256) void bscan_kernel(
    const int* __restrict__ bsum, int* __restrict__ bbase)
{
  __shared__ int tmp[256];
  const int t = threadIdx.x;
  const int b = t * PERT;
  const int e = min(b + PERT, NCHUNK8);
  int s = 0;
  for (int i = b; i < e; ++i) s += bsum[i];
  tmp[t] = s;
  __syncthreads();
#pragma unroll
  for (int off = 1; off < 256; off <<= 1) {
    const int x = (t >= off) ? tmp[t - off] : 0;
    __syncthreads();
    tmp[t] += x;
    __syncthreads();
  }
  int run = tmp[t] - s;        // exclusive base of this thread's chunk
  for (int i = b; i < e; ++i) {
    const int v = bsum[i];
    bbase[i] = run;
    run += v;
  }
}

__global__ __launch_bounds__(256) void expand_kernel(
    int* deg, const int* __restrict__ bbase, int* __restrict__ offsets)
{
  __shared__ int tmp[256];
  const int t = threadIdx.x;
  const int i = blockIdx.x * 256 + t;
  const int v = (i < NB) ? deg[i] : 0;
  tmp[t] = v;
  __syncthreads();
#pragma unroll
  for (int off = 1; off < 256; off <<= 1) {
    const int x = (t >= off) ? tmp[t - off] : 0;
    __syncthreads();
    tmp[t] += x;
    __syncthreads();
  }
  const int base = bbase[blockIdx.x];
  const int excl = base + tmp[t] - v;
  if (i < NB) {
    offsets[i] = excl;
    deg[i] = excl;                  // fill cursor
    if (i == NB - 1) offsets[NB] = base + tmp[t];
  }
}

// eidx[pos] = src, bucketed by (dst,rel)
__global__ __launch_bounds__(256) void fill_kernel(
    const int* __restrict__ src, const int* __restrict__ dst,
    const int* __restrict__ et, int* __restrict__ cursor,
    int* __restrict__ eidx)
{
  const int e = blockIdx.x * 256 + threadIdx.x;
  if (e < NE) {
    const int pos = atomicAdd(&cursor[dst[e] * NR + et[e]], 1);
    eidx[pos] = src[e];
  }
}

// ---------------- gather helpers ----------------
__device__ __forceinline__ void gacc_row(
    const unsigned short* __restrict__ h, int idx, int g, float s[4][8])
{
  const unsigned short* hp = h + (size_t)idx * DD + g * 8;
#pragma unroll
  for (int ks = 0; ks < 4; ++ks) {
    const uint4 q = *reinterpret_cast<const uint4*>(hp + ks * 32);
    s[ks][0] += bflo(q.x); s[ks][1] += bfhi(q.x);
    s[ks][2] += bflo(q.y); s[ks][3] += bfhi(q.y);
    s[ks][4] += bflo(q.z); s[ks][5] += bfhi(q.z);
    s[ks][6] += bflo(q.w); s[ks][7] += bfhi(q.w);
  }
}

// sum h[src] rows of one (dst,rel) bin into a B-fragment; first 4 indices prefetched
__device__ __forceinline__ void gather_accum(
    const unsigned short* __restrict__ h, const int* __restrict__ eidx,
    int pb, int ne, int pe0, int pe1, int pe2, int pe3, int g, bf16x8* frag)
{
  float s[4][8];
#pragma unroll
  for (int ks = 0; ks < 4; ++ks)
#pragma unroll
    for (int j = 0; j < 8; ++j) s[ks][j] = 0.f;
  if (ne > 0) gacc_row(h, pe0, g, s);
  if (ne > 1) gacc_row(h, pe1, g, s);
  if (ne > 2) gacc_row(h, pe2, g, s);
  if (ne > 3) gacc_row(h, pe3, g, s);
  for (int j = 4; j < ne; ++j) gacc_row(h, eidx[pb + j], g, s);
#pragma unroll
  for (int ks = 0; ks < 4; ++ks) {
    uint4 u;
    u.x = pk2(s[ks][0], s[ks][1]);
    u.y = pk2(s[ks][2], s[ks][3]);
    u.z = pk2(s[ks][4], s[ks][5]);
    u.w = pk2(s[ks][6], s[ks][7]);
    frag[ks] = *reinterpret_cast<bf16x8*>(&u);
  }
}

// ---------------- fused RGCN layer: gather + GEMM, single 32KB W buffer ----------------
// block = 128 dst nodes (8 waves x 16); offsets preloaded; eidx prefetched per step.
template<int OUTF32>
__global__ __launch_bounds__(512, 4) void layer_kernel(
    const unsigned short* __restrict__ h,      // [NN][128] bf16 (read-only)
    const int* __restrict__ off8, const int* __restrict__ eidx,
    const unsigned short* __restrict__ WTl,    // this layer: [9][128][128] bf16 [o][d]
    const float* __restrict__ bias,
    void* __restrict__ out)                    // [NN][128] bf16 or f32
{
  __shared__ __align__(16) char ldsW[DD * DD * 2];   // 32 KB, XOR-swizzled

  const int tid = threadIdx.x;
  const int rowBase = blockIdx.x * 128;
  const int lane = tid & 63;
  const int w = tid >> 6;            // 0..7
  const int c = lane & 15;           // n selector
  const int g = lane >> 4;           // k group
  const int n = rowBase + w * 16 + c;
  const int nld = (n < NN) ? n : (NN - 1);

  // staging geometry: dst linear 16B chunks, src pre-inverse-swizzled
  int srcOff[4];
#pragma unroll
  for (int j = 0; j < 4; ++j) {
    const int dstB = (tid + j * 512) * 16;
    const int srcB = dstB ^ (((dstB >> 8) & 7) << 4);
    srcOff[j] = srcB >> 1;
  }

  // preload all 9 CSR offsets for this node (static-indexed by unrolled steps)
  int ob[9];
#pragma unroll
  for (int k = 0; k < 9; ++k) ob[k] = off8[nld * NR + k];

  // prologue: issue W[0] loads, overlap with rel-0 gather, then stage + barrier
  uint4 wreg[4];
#pragma unroll
  for (int j = 0; j < 4; ++j)
    wreg[j] = *reinterpret_cast<const uint4*>(WTl + srcOff[j]);

  bf16x8 fA[4], fB[4];
  {
    const int pb = ob[0], ne = ob[1] - ob[0];
    const int pe0 = eidx[min(pb + 0, NE - 1)];
    const int pe1 = eidx[min(pb + 1, NE - 1)];
    const int pe2 = eidx[min(pb + 2, NE - 1)];
    const int pe3 = eidx[min(pb + 3, NE - 1)];
    gather_accum(h, eidx, pb, ne, pe0, pe1, pe2, pe3, g, fA);
  }

#pragma unroll
  for (int j = 0; j < 4; ++j)
    *reinterpret_cast<uint4*>(ldsW + (tid + j * 512) * 16) = wreg[j];
  __syncthreads();

  f32x4 acc[8];
#pragma unroll
  for (int t = 0; t < 8; ++t) acc[t] = (f32x4){0.f, 0.f, 0.f, 0.f};

#define LSTEP(R, CUR, NXT)                                                            \
  {                                                                                   \
    int pb = 0, pne = 0, pe0 = 0, pe1 = 0, pe2 = 0, pe3 = 0;                          \
    if ((R) + 1 < NR) {                                                               \
      pb = ob[(R) + 1]; pne = ob[(R) + 2] - pb;                                       \
      pe0 = eidx[min(pb + 0, NE - 1)];                                                \
      pe1 = eidx[min(pb + 1, NE - 1)];                                                \
      pe2 = eidx[min(pb + 2, NE - 1)];                                                \
      pe3 = eidx[min(pb + 3, NE - 1)];                                                \
    }                                                                                 \
    _Pragma("unroll")                                                                 \
    for (int ks = 0; ks < 4; ++ks) {                                                  \
      _Pragma("unroll")                                                               \
      for (int t = 0; t < 8; ++t) {                                                   \
        const int addr = (((t * 16 + c) << 8) + (ks << 6) + (g << 4)) ^ ((c & 7) << 4); \
        bf16x8 a = *reinterpret_cast<const bf16x8*>(ldsW + addr);                     \
        acc[t] = __builtin_amdgcn_mfma_f32_16x16x32_bf16(a, CUR[ks], acc[t], 0, 0, 0); \
      }                                                                               \
    }                                                                                 \
    if ((R) + 1 < NR) {                                                               \
      gather_accum(h, eidx, pb, pne, pe0, pe1, pe2, pe3, g, NXT);                     \
    } else if ((R) == NR - 1) {                                                       \
      _Pragma("unroll")                                                               \
      for (int ks = 0; ks < 4; ++ks)                                                  \
        NXT[ks] = *reinterpret_cast<const bf16x8*>(h + (size_t)nld * DD + ks * 32 + g * 8); \
    }                                                                                 \
    if ((R) < NR) {                                                                   \
      const unsigned short* wnext = WTl + (size_t)((R) + 1) * DD * DD;                \
      _Pragma("unroll")                                                               \
      for (int j = 0; j < 4; ++j)                                                     \
        wreg[j] = *reinterpret_cast<const uint4*>(wnext + srcOff[j]);                 \
      __syncthreads();                                                                \
      _Pragma("unroll")                                                               \
      for (int j = 0; j < 4; ++j)                                                     \
        *reinterpret_cast<uint4*>(ldsW + (tid + j * 512) * 16) = wreg[j];             \
      __syncthreads();                                                                \
    }                                                                                 \
  }

  LSTEP(0, fA, fB) LSTEP(1, fB, fA) LSTEP(2, fA, fB) LSTEP(3, fB, fA)
  LSTEP(4, fA, fB) LSTEP(5, fB, fA) LSTEP(6, fA, fB) LSTEP(7, fB, fA)
  LSTEP(8, fA, fB)
#undef LSTEP

  if (n >= NN) return;
  if (OUTF32) {
    float* dst = (float*)out + (size_t)n * DD;
#pragma unroll
    for (int t = 0; t < 8; ++t) {
      const int o0 = t * 16 + g * 4;
      const float4 bv = *reinterpret_cast<const float4*>(bias + o0);
      float4 o;
      o.x = acc[t][0] + bv.x; o.y = acc[t][1] + bv.y;
      o.z = acc[t][2] + bv.z; o.w = acc[t][3] + bv.w;
      *reinterpret_cast<float4*>(dst + o0) = o;
    }
  } else {
    unsigned short* dst = (unsigned short*)out + (size_t)n * DD;
#pragma unroll
    for (int t = 0; t < 8; ++t) {
      const int o0 = t * 16 + g * 4;
      const float4 bv = *reinterpret_cast<const float4*>(bias + o0);
      uint2 q;
      q.x = pk2(acc[t][0] + bv.x, acc[t][1] + bv.y);
      q.y = pk2(acc[t][2] + bv.z, acc[t][3] + bv.w);
      *reinterpret_cast<uint2*>(dst + o0) = q;
    }
  }
}

extern "C" void kernel_launch(void* const* d_in, const int* in_sizes, int n_in,
                              void* d_out, int out_size, void* d_ws, size_t ws_size,
                              hipStream_t stream) {
  const int*   node_ids = (const int*)d_in[0];
  const int*   src   = (const int*)d_in[1];
  const int*   dst   = (const int*)d_in[2];
  const int*   etype = (const int*)d_in[3];
  const float* emb   = (const float*)d_in[4];
  const float* W1    = (const float*)d_in[5];
  const float* Ws1   = (const float*)d_in[6];
  const float* b1    = (const float*)d_in[7];
  const float* W2    = (const float*)d_in[8];
  const float* Ws2   = (const float*)d_in[9];
  const float* b2    = (const float*)d_in[10];

  // ws layout (~35 MB):
  //   h0     bf16 [NN*DD]       12.8 MB
  //   h1     bf16 [NN*DD]       12.8 MB
  //   WT     bf16 [18*DD*DD]     0.59 MB
  //   off8   i32  [NB+1]         1.6 MB
  //   deg8   i32  [NB]           1.6 MB
  //   eidx   i32  [NE]           2.4 MB
  //   bsum/bbase i32 [NCHUNK8]
  char* p = (char*)d_ws;
  unsigned short* h0 = (unsigned short*)p;  p += (size_t)NN * DD * 2;
  unsigned short* h1 = (unsigned short*)p;  p += (size_t)NN * DD * 2;
  unsigned short* WT = (unsigned short*)p;  p += (size_t)18 * DD * DD * 2;
  int* off8          = (int*)p;             p += (size_t)(NB + 1) * 4;
  int* deg8          = (int*)p;             p += (size_t)NB * 4;
  int* eidx          = (int*)p;             p += (size_t)NE * 4;
  int* bsum          = (int*)p;             p += (size_t)NCHUNK8 * 4;
  int* bbase         = (int*)p;

  const int eb = (NE + 255) / 256;
  const int tb = (NN + 127) / 128;   // 391

  // weight convert + h0 convert + CSR build over (dst,rel)
  convw_kernel<<<dim3(DD, 18), 128, 0, stream>>>(W1, Ws1, W2, Ws2, WT);
  convh_kernel<<<(NN * 16) / 256, 256, 0, stream>>>(emb, node_ids, h0);
  hipMemsetAsync(deg8, 0, (size_t)NB * 4, stream);
  hist_kernel<<<eb, 256, 0, stream>>>(dst, etype, deg8);
  bsum_kernel<<<NCHUNK8, 256, 0, stream>>>(deg8, bsum);
  bscan_kernel<<<1, 256, 0, stream>>>(bsum, bbase);
  expand_kernel<<<NCHUNK8, 256, 0, stream>>>(deg8, bbase, off8);
  fill_kernel<<<eb, 256, 0, stream>>>(src, dst, etype, deg8, eidx);

  // fused layers (no s materialization)
  layer_kernel<0><<<tb, 512, 0, stream>>>(h0, off8, eidx, WT, b1, h1);
  layer_kernel<1><<<tb, 512, 0, stream>>>(h1, off8, eidx, WT + (size_t)9 * DD * DD, b2, (float*)d_out);
}

// Round 13
// 251.960 us; speedup vs baseline: 1.2630x; 1.2630x over previous
//
#include <hip/hip_runtime.h>
#include <hip/hip_bf16.h>

#define NN 50000
#define NE 600000
#define DD 128
#define NR 8
#define NB (NN * NR)                   // 400000 (dst,rel) bins
#define NCHUNK8 ((NB + 255) / 256)     // 1563 scan blocks
#define PERT ((NCHUNK8 + 255) / 256)   // 7 items/thread in bscan

typedef __attribute__((ext_vector_type(8))) short bf16x8;
typedef __attribute__((ext_vector_type(4))) float f32x4;

__device__ __forceinline__ unsigned short f2bf(float f) {
  __hip_bfloat16 h = __float2bfloat16(f);
  return *reinterpret_cast<unsigned short*>(&h);
}
__device__ __forceinline__ unsigned pk2(float lo, float hi) {
  return (unsigned)f2bf(lo) | ((unsigned)f2bf(hi) << 16);
}
__device__ __forceinline__ float bflo(unsigned u) { return __uint_as_float(u << 16); }
__device__ __forceinline__ float bfhi(unsigned u) { return __uint_as_float(u & 0xffff0000u); }

// ---------------- weight transpose+convert: WT[m][o][d] = bf16(W[m][d][o]) ----------------
__global__ __launch_bounds__(128) void convw_kernel(
    const float* __restrict__ W1, const float* __restrict__ Ws1,
    const float* __restrict__ W2, const float* __restrict__ Ws2,
    unsigned short* __restrict__ WT)
{
  const int m = blockIdx.y, o = blockIdx.x, d = threadIdx.x;
  const float* src;
  if (m < 8)       src = W1 + (size_t)m * DD * DD;
  else if (m == 8) src = Ws1;
  else if (m < 17) src = W2 + (size_t)(m - 9) * DD * DD;
  else             src = Ws2;
  WT[(size_t)m * DD * DD + o * DD + d] = f2bf(src[(size_t)d * DD + o]);
}

// ---------------- h0 = bf16(emb[node_ids]) ----------------
__global__ __launch_bounds__(256) void convh_kernel(
    const float* __restrict__ emb, const int* __restrict__ ids,
    unsigned short* __restrict__ h)
{
  const int gid = blockIdx.x * 256 + threadIdx.x;   // NN*16 total
  if (gid >= NN * 16) return;
  const int row = gid >> 4;
  const int off = (gid & 15) * 8;
  const int srcRow = ids[row];
  const float* src = emb + (size_t)srcRow * DD + off;
  const float4 a = *reinterpret_cast<const float4*>(src);
  const float4 b = *reinterpret_cast<const float4*>(src + 4);
  uint4 u;
  u.x = pk2(a.x, a.y); u.y = pk2(a.z, a.w);
  u.z = pk2(b.x, b.y); u.w = pk2(b.z, b.w);
  *reinterpret_cast<uint4*>(h + (size_t)row * DD + off) = u;
}

// ---------------- CSR build over (dst,rel) bins ----------------
__global__ __launch_bounds__(256) void hist_kernel(
    const int* __restrict__ dst, const int* __restrict__ et,
    int* __restrict__ deg)
{
  const int e = blockIdx.x * 256 + threadIdx.x;
  if (e < NE) atomicAdd(&deg[dst[e] * NR + et[e]], 1);
}

__global__ __launch_bounds__(256) void bsum_kernel(
    const int* __restrict__ deg, int* __restrict__ bsum)
{
  __shared__ int tmp[256];
  const int t = threadIdx.x;
  const int i = blockIdx.x * 256 + t;
  tmp[t] = (i < NB) ? deg[i] : 0;
  __syncthreads();
#pragma unroll
  for (int off = 128; off > 0; off >>= 1) {
    if (t < off) tmp[t] += tmp[t + off];
    __syncthreads();
  }
  if (t == 0) bsum[blockIdx.x] = tmp[0];
}

// 1 block: exclusive scan of bsum[NCHUNK8] -> bbase[NCHUNK8]; 7 items/thread
__global__ __launch_bounds__(256) void bscan_kernel(
    const int* __restrict__ bsum, int* __restrict__ bbase)
{
  __shared__ int tmp[256];
  const int t = threadIdx.x;
  const int b = t * PERT;
  const int e = min(b + PERT, NCHUNK8);
  int s = 0;
  for (int i = b; i < e; ++i) s += bsum[i];
  tmp[t] = s;
  __syncthreads();
#pragma unroll
  for (int off = 1; off < 256; off <<= 1) {
    const int x = (t >= off) ? tmp[t - off] : 0;
    __syncthreads();
    tmp[t] += x;
    __syncthreads();
  }
  int run = tmp[t] - s;        // exclusive base of this thread's chunk
  for (int i = b; i < e; ++i) {
    const int v = bsum[i];
    bbase[i] = run;
    run += v;
  }
}

__global__ __launch_bounds__(256) void expand_kernel(
    int* deg, const int* __restrict__ bbase, int* __restrict__ offsets)
{
  __shared__ int tmp[256];
  const int t = threadIdx.x;
  const int i = blockIdx.x * 256 + t;
  const int v = (i < NB) ? deg[i] : 0;
  tmp[t] = v;
  __syncthreads();
#pragma unroll
  for (int off = 1; off < 256; off <<= 1) {
    const int x = (t >= off) ? tmp[t - off] : 0;
    __syncthreads();
    tmp[t] += x;
    __syncthreads();
  }
  const int base = bbase[blockIdx.x];
  const int excl = base + tmp[t] - v;
  if (i < NB) {
    offsets[i] = excl;
    deg[i] = excl;                  // fill cursor
    if (i == NB - 1) offsets[NB] = base + tmp[t];
  }
}

// eidx[pos] = src, bucketed by (dst,rel)
__global__ __launch_bounds__(256) void fill_kernel(
    const int* __restrict__ src, const int* __restrict__ dst,
    const int* __restrict__ et, int* __restrict__ cursor,
    int* __restrict__ eidx)
{
  const int e = blockIdx.x * 256 + threadIdx.x;
  if (e < NE) {
    const int pos = atomicAdd(&cursor[dst[e] * NR + et[e]], 1);
    eidx[pos] = src[e];
  }
}

// ---------------- gather helpers (R10-proven, no extra live state) ----------------
__device__ __forceinline__ void gacc_row(
    const unsigned short* __restrict__ h, int idx, int g, float s[4][8])
{
  const unsigned short* hp = h + (size_t)idx * DD + g * 8;
#pragma unroll
  for (int ks = 0; ks < 4; ++ks) {
    const uint4 q = *reinterpret_cast<const uint4*>(hp + ks * 32);
    s[ks][0] += bflo(q.x); s[ks][1] += bfhi(q.x);
    s[ks][2] += bflo(q.y); s[ks][3] += bfhi(q.y);
    s[ks][4] += bflo(q.z); s[ks][5] += bfhi(q.z);
    s[ks][6] += bflo(q.w); s[ks][7] += bfhi(q.w);
  }
}

__device__ __forceinline__ void gather_frag(
    const unsigned short* __restrict__ h,
    const int* __restrict__ eidx,
    int beg, int end, int g, bf16x8* frag)
{
  float s[4][8];
#pragma unroll
  for (int ks = 0; ks < 4; ++ks)
#pragma unroll
    for (int j = 0; j < 8; ++j) s[ks][j] = 0.f;
  for (int i = beg; i < end; ++i) gacc_row(h, eidx[i], g, s);
#pragma unroll
  for (int ks = 0; ks < 4; ++ks) {
    uint4 u;
    u.x = pk2(s[ks][0], s[ks][1]);
    u.y = pk2(s[ks][2], s[ks][3]);
    u.z = pk2(s[ks][4], s[ks][5]);
    u.w = pk2(s[ks][6], s[ks][7]);
    frag[ks] = *reinterpret_cast<bf16x8*>(&u);
  }
}

// ---------------- fused RGCN layer: 64 nodes/block, K-half W staging ----------------
// 256 thr = 4 waves x 16 nodes. 18 phases: (rel 0..8) x (k-half 0,1).
// LDS: 2 x 16KB dbuf; W[r] k-half staged one phase ahead. Fragments ping-pong per relation.
template<int OUTF32>
__global__ __launch_bounds__(256, 4) void layer_kernel(
    const unsigned short* __restrict__ h,      // [NN][128] bf16 (read-only)
    const int* __restrict__ off8, const int* __restrict__ eidx,
    const unsigned short* __restrict__ WTl,    // this layer: [9][128][128] bf16 [o][d]
    const float* __restrict__ bias,
    void* __restrict__ out)                    // [NN][128] bf16 or f32
{
  __shared__ __align__(16) char ldsW[2][DD * 64 * 2];   // 2 x 16 KB, XOR-swizzled

  const int tid = threadIdx.x;
  const int rowBase = blockIdx.x * 64;
  const int lane = tid & 63;
  const int w = tid >> 6;            // 0..3
  const int c = lane & 15;           // node selector
  const int g = lane >> 4;           // k group
  const int n = rowBase + w * 16 + c;
  const int nld = (n < NN) ? n : (NN - 1);

  // staging geometry: 1024 chunks of 16B per half; thread owns 4.
  // LDS row = 128B (64 bf16); swizzle byte ^= (o&7)<<4.
  int dstB[4], srcRel[4];
#pragma unroll
  for (int j = 0; j < 4; ++j) {
    const int i = tid + j * 256;     // 0..1023
    const int o = i >> 3, slot = i & 7;
    dstB[j] = ((o << 7) | (slot << 4)) ^ ((o & 7) << 4);
    srcRel[j] = o * DD + slot * 8;   // element offset within a W matrix (k-half added later)
  }

  // prologue: gather relation 0; stage W[0] half0 into buf0
  bf16x8 fA[4], fB[4];
  gather_frag(h, eidx, off8[nld * NR], off8[nld * NR + 1], g, fA);

  uint4 wreg[4];
#pragma unroll
  for (int j = 0; j < 4; ++j)
    wreg[j] = *reinterpret_cast<const uint4*>(WTl + srcRel[j]);
#pragma unroll
  for (int j = 0; j < 4; ++j)
    *reinterpret_cast<uint4*>(ldsW[0] + dstB[j]) = wreg[j];

  f32x4 acc[8];
#pragma unroll
  for (int t = 0; t < 8; ++t) acc[t] = (f32x4){0.f, 0.f, 0.f, 0.f};

  // phase P: r=P>>1, hf=P&1; reads buf[P&1]; stages phase P+1 into buf[(P+1)&1];
  // gathers relation r+1 on even phases (hf==0).
#define PH(P, CUR, NXT)                                                               \
  {                                                                                   \
    __syncthreads();                                                                  \
    if ((P) < 17) {                                                                   \
      const unsigned short* wsrc = WTl                                                \
          + (size_t)(((P) + 1) >> 1) * DD * DD + (((P) + 1) & 1) * 64;                \
      _Pragma("unroll")                                                               \
      for (int j = 0; j < 4; ++j)                                                     \
        wreg[j] = *reinterpret_cast<const uint4*>(wsrc + srcRel[j]);                  \
    }                                                                                 \
    int gb = 0, ge = 0;                                                               \
    if (((P) & 1) == 0 && ((P) >> 1) + 1 < NR) {                                      \
      gb = off8[nld * NR + ((P) >> 1) + 1];                                           \
      ge = off8[nld * NR + ((P) >> 1) + 2];                                           \
    }                                                                                 \
    _Pragma("unroll")                                                                 \
    for (int kl = 0; kl < 2; ++kl) {                                                  \
      _Pragma("unroll")                                                               \
      for (int t = 0; t < 8; ++t) {                                                   \
        const int addr = (((t * 16 + c) << 7) + ((kl * 4 + g) << 4)) ^ ((c & 7) << 4); \
        bf16x8 a = *reinterpret_cast<const bf16x8*>(ldsW[(P) & 1] + addr);            \
        acc[t] = __builtin_amdgcn_mfma_f32_16x16x32_bf16(                             \
            a, CUR[((P) & 1) * 2 + kl], acc[t], 0, 0, 0);                             \
      }                                                                               \
    }                                                                                 \
    if (((P) & 1) == 0) {                                                             \
      if (((P) >> 1) + 1 < NR) {                                                      \
        gather_frag(h, eidx, gb, ge, g, NXT);                                         \
      } else if (((P) >> 1) + 1 == NR) {                                              \
        _Pragma("unroll")                                                             \
        for (int ks = 0; ks < 4; ++ks)                                                \
          NXT[ks] = *reinterpret_cast<const bf16x8*>(                                 \
              h + (size_t)nld * DD + ks * 32 + g * 8);                                \
      }                                                                               \
    }                                                                                 \
    if ((P) < 17) {                                                                   \
      _Pragma("unroll")                                                               \
      for (int j = 0; j < 4; ++j)                                                     \
        *reinterpret_cast<uint4*>(ldsW[((P) + 1) & 1] + dstB[j]) = wreg[j];           \
    }                                                                                 \
  }

  PH(0, fA, fB)  PH(1, fA, fB)
  PH(2, fB, fA)  PH(3, fB, fA)
  PH(4, fA, fB)  PH(5, fA, fB)
  PH(6, fB, fA)  PH(7, fB, fA)
  PH(8, fA, fB)  PH(9, fA, fB)
  PH(10, fB, fA) PH(11, fB, fA)
  PH(12, fA, fB) PH(13, fA, fB)
  PH(14, fB, fA) PH(15, fB, fA)
  PH(16, fA, fB) PH(17, fA, fB)
#undef PH

  if (n >= NN) return;
  if (OUTF32) {
    float* dst = (float*)out + (size_t)n * DD;
#pragma unroll
    for (int t = 0; t < 8; ++t) {
      const int o0 = t * 16 + g * 4;
      const float4 bv = *reinterpret_cast<const float4*>(bias + o0);
      float4 o;
      o.x = acc[t][0] + bv.x; o.y = acc[t][1] + bv.y;
      o.z = acc[t][2] + bv.z; o.w = acc[t][3] + bv.w;
      *reinterpret_cast<float4*>(dst + o0) = o;
    }
  } else {
    unsigned short* dst = (unsigned short*)out + (size_t)n * DD;
#pragma unroll
    for (int t = 0; t < 8; ++t) {
      const int o0 = t * 16 + g * 4;
      const float4 bv = *reinterpret_cast<const float4*>(bias + o0);
      uint2 q;
      q.x = pk2(acc[t][0] + bv.x, acc[t][1] + bv.y);
      q.y = pk2(acc[t][2] + bv.z, acc[t][3] + bv.w);
      *reinterpret_cast<uint2*>(dst + o0) = q;
    }
  }
}

extern "C" void kernel_launch(void* const* d_in, const int* in_sizes, int n_in,
                              void* d_out, int out_size, void* d_ws, size_t ws_size,
                              hipStream_t stream) {
  const int*   node_ids = (const int*)d_in[0];
  const int*   src   = (const int*)d_in[1];
  const int*   dst   = (const int*)d_in[2];
  const int*   etype = (const int*)d_in[3];
  const float* emb   = (const float*)d_in[4];
  const float* W1    = (const float*)d_in[5];
  const float* Ws1   = (const float*)d_in[6];
  const float* b1    = (const float*)d_in[7];
  const float* W2    = (const float*)d_in[8];
  const float* Ws2   = (const float*)d_in[9];
  const float* b2    = (const float*)d_in[10];

  // ws layout (~35 MB):
  //   h0     bf16 [NN*DD]       12.8 MB
  //   h1     bf16 [NN*DD]       12.8 MB
  //   WT     bf16 [18*DD*DD]     0.59 MB
  //   off8   i32  [NB+1]         1.6 MB
  //   deg8   i32  [NB]           1.6 MB
  //   eidx   i32  [NE]           2.4 MB
  //   bsum/bbase i32 [NCHUNK8]
  char* p = (char*)d_ws;
  unsigned short* h0 = (unsigned short*)p;  p += (size_t)NN * DD * 2;
  unsigned short* h1 = (unsigned short*)p;  p += (size_t)NN * DD * 2;
  unsigned short* WT = (unsigned short*)p;  p += (size_t)18 * DD * DD * 2;
  int* off8          = (int*)p;             p += (size_t)(NB + 1) * 4;
  int* deg8          = (int*)p;             p += (size_t)NB * 4;
  int* eidx          = (int*)p;             p += (size_t)NE * 4;
  int* bsum          = (int*)p;             p += (size_t)NCHUNK8 * 4;
  int* bbase         = (int*)p;

  const int eb = (NE + 255) / 256;
  const int tb = (NN + 63) / 64;     // 782

  // weight convert + h0 convert + CSR build over (dst,rel)
  convw_kernel<<<dim3(DD, 18), 128, 0, stream>>>(W1, Ws1, W2, Ws2, WT);
  convh_kernel<<<(NN * 16) / 256, 256, 0, stream>>>(emb, node_ids, h0);
  hipMemsetAsync(deg8, 0, (size_t)NB * 4, stream);
  hist_kernel<<<eb, 256, 0, stream>>>(dst, etype, deg8);
  bsum_kernel<<<NCHUNK8, 256, 0, stream>>>(deg8, bsum);
  bscan_kernel<<<1, 256, 0, stream>>>(bsum, bbase);
  expand_kernel<<<NCHUNK8, 256, 0, stream>>>(deg8, bbase, off8);
  fill_kernel<<<eb, 256, 0, stream>>>(src, dst, etype, deg8, eidx);

  // fused layers (no s materialization)
  layer_kernel<0><<<tb, 256, 0, stream>>>(h0, off8, eidx, WT, b1, h1);
  layer_kernel<1><<<tb, 256, 0, stream>>>(h1, off8, eidx, WT + (size_t)9 * DD * DD, b2, (float*)d_out);
}

// Round 14
// 235.374 us; speedup vs baseline: 1.3520x; 1.0705x over previous
//
#include <hip/hip_runtime.h>
#include <hip/hip_bf16.h>

#define NN 50000
#define NE 600000
#define DD 128
#define NR 8
#define NB (NN * NR)                   // 400000 (dst,rel) bins
#define NCHUNK8 ((NB + 255) / 256)     // 1563 scan blocks
#define PERT ((NCHUNK8 + 255) / 256)   // 7 items/thread in bscan
#define CAPE 1024                      // LDS edge-slice capacity per block

typedef __attribute__((ext_vector_type(8))) short bf16x8;
typedef __attribute__((ext_vector_type(4))) float f32x4;

__device__ __forceinline__ unsigned short f2bf(float f) {
  __hip_bfloat16 h = __float2bfloat16(f);
  return *reinterpret_cast<unsigned short*>(&h);
}
__device__ __forceinline__ unsigned pk2(float lo, float hi) {
  return (unsigned)f2bf(lo) | ((unsigned)f2bf(hi) << 16);
}
__device__ __forceinline__ float bflo(unsigned u) { return __uint_as_float(u << 16); }
__device__ __forceinline__ float bfhi(unsigned u) { return __uint_as_float(u & 0xffff0000u); }

// ---------------- weight transpose+convert: WT[m][o][d] = bf16(W[m][d][o]) ----------------
__global__ __launch_bounds__(128) void convw_kernel(
    const float* __restrict__ W1, const float* __restrict__ Ws1,
    const float* __restrict__ W2, const float* __restrict__ Ws2,
    unsigned short* __restrict__ WT)
{
  const int m = blockIdx.y, o = blockIdx.x, d = threadIdx.x;
  const float* src;
  if (m < 8)       src = W1 + (size_t)m * DD * DD;
  else if (m == 8) src = Ws1;
  else if (m < 17) src = W2 + (size_t)(m - 9) * DD * DD;
  else             src = Ws2;
  WT[(size_t)m * DD * DD + o * DD + d] = f2bf(src[(size_t)d * DD + o]);
}

// ---------------- h0 = bf16(emb[node_ids]) ----------------
__global__ __launch_bounds__(256) void convh_kernel(
    const float* __restrict__ emb, const int* __restrict__ ids,
    unsigned short* __restrict__ h)
{
  const int gid = blockIdx.x * 256 + threadIdx.x;   // NN*16 total
  if (gid >= NN * 16) return;
  const int row = gid >> 4;
  const int off = (gid & 15) * 8;
  const int srcRow = ids[row];
  const float* src = emb + (size_t)srcRow * DD + off;
  const float4 a = *reinterpret_cast<const float4*>(src);
  const float4 b = *reinterpret_cast<const float4*>(src + 4);
  uint4 u;
  u.x = pk2(a.x, a.y); u.y = pk2(a.z, a.w);
  u.z = pk2(b.x, b.y); u.w = pk2(b.z, b.w);
  *reinterpret_cast<uint4*>(h + (size_t)row * DD + off) = u;
}

// ---------------- CSR build over (dst,rel) bins ----------------
__global__ __launch_bounds__(256) void hist_kernel(
    const int* __restrict__ dst, const int* __restrict__ et,
    int* __restrict__ deg)
{
  const int e = blockIdx.x * 256 + threadIdx.x;
  if (e < NE) atomicAdd(&deg[dst[e] * NR + et[e]], 1);
}

__global__ __launch_bounds__(256) void bsum_kernel(
    const int* __restrict__ deg, int* __restrict__ bsum)
{
  __shared__ int tmp[256];
  const int t = threadIdx.x;
  const int i = blockIdx.x * 256 + t;
  tmp[t] = (i < NB) ? deg[i] : 0;
  __syncthreads();
#pragma unroll
  for (int off = 128; off > 0; off >>= 1) {
    if (t < off) tmp[t] += tmp[t + off];
    __syncthreads();
  }
  if (t == 0) bsum[blockIdx.x] = tmp[0];
}

// 1 block: exclusive scan of bsum[NCHUNK8] -> bbase[NCHUNK8]; 7 items/thread
__global__ __launch_bounds__(256) void bscan_kernel(
    const int* __restrict__ bsum, int* __restrict__ bbase)
{
  __shared__ int tmp[256];
  const int t = threadIdx.x;
  const int b = t * PERT;
  const int e = min(b + PERT, NCHUNK8);
  int s = 0;
  for (int i = b; i < e; ++i) s += bsum[i];
  tmp[t] = s;
  __syncthreads();
#pragma unroll
  for (int off = 1; off < 256; off <<= 1) {
    const int x = (t >= off) ? tmp[t - off] : 0;
    __syncthreads();
    tmp[t] += x;
    __syncthreads();
  }
  int run = tmp[t] - s;        // exclusive base of this thread's chunk
  for (int i = b; i < e; ++i) {
    const int v = bsum[i];
    bbase[i] = run;
    run += v;
  }
}

__global__ __launch_bounds__(256) void expand_kernel(
    int* deg, const int* __restrict__ bbase, int* __restrict__ offsets)
{
  __shared__ int tmp[256];
  const int t = threadIdx.x;
  const int i = blockIdx.x * 256 + t;
  const int v = (i < NB) ? deg[i] : 0;
  tmp[t] = v;
  __syncthreads();
#pragma unroll
  for (int off = 1; off < 256; off <<= 1) {
    const int x = (t >= off) ? tmp[t - off] : 0;
    __syncthreads();
    tmp[t] += x;
    __syncthreads();
  }
  const int base = bbase[blockIdx.x];
  const int excl = base + tmp[t] - v;
  if (i < NB) {
    offsets[i] = excl;
    deg[i] = excl;                  // fill cursor
    if (i == NB - 1) offsets[NB] = base + tmp[t];
  }
}

// eidx[pos] = src, bucketed by (dst,rel)
__global__ __launch_bounds__(256) void fill_kernel(
    const int* __restrict__ src, const int* __restrict__ dst,
    const int* __restrict__ et, int* __restrict__ cursor,
    int* __restrict__ eidx)
{
  const int e = blockIdx.x * 256 + threadIdx.x;
  if (e < NE) {
    const int pos = atomicAdd(&cursor[dst[e] * NR + et[e]], 1);
    eidx[pos] = src[e];
  }
}

// ---------------- gather helpers ----------------
__device__ __forceinline__ void gacc_row(
    const unsigned short* __restrict__ h, int idx, int g, float s[4][8])
{
  const unsigned short* hp = h + (size_t)idx * DD + g * 8;
#pragma unroll
  for (int ks = 0; ks < 4; ++ks) {
    const uint4 q = *reinterpret_cast<const uint4*>(hp + ks * 32);
    s[ks][0] += bflo(q.x); s[ks][1] += bfhi(q.x);
    s[ks][2] += bflo(q.y); s[ks][3] += bfhi(q.y);
    s[ks][4] += bflo(q.z); s[ks][5] += bfhi(q.z);
    s[ks][6] += bflo(q.w); s[ks][7] += bfhi(q.w);
  }
}

// sum h[src] rows for [beg,end); indices from LDS slice (global fallback past CAPE)
__device__ __forceinline__ void gather_frag_lds(
    const unsigned short* __restrict__ h,
    const int* __restrict__ eidx, const int* ldsE, int blockBeg,
    int beg, int end, int g, bf16x8* frag)
{
  float s[4][8];
#pragma unroll
  for (int ks = 0; ks < 4; ++ks)
#pragma unroll
    for (int j = 0; j < 8; ++j) s[ks][j] = 0.f;
  for (int i = beg; i < end; ++i) {
    const int li = i - blockBeg;
    const int idx = (li < CAPE) ? ldsE[li] : eidx[i];
    gacc_row(h, idx, g, s);
  }
#pragma unroll
  for (int ks = 0; ks < 4; ++ks) {
    uint4 u;
    u.x = pk2(s[ks][0], s[ks][1]);
    u.y = pk2(s[ks][2], s[ks][3]);
    u.z = pk2(s[ks][4], s[ks][5]);
    u.w = pk2(s[ks][6], s[ks][7]);
    frag[ks] = *reinterpret_cast<bf16x8*>(&u);
  }
}

// ---------------- fused RGCN layer: 64 nodes/block, K-half W staging ----------------
// 256 thr = 4 waves x 16 nodes. 18 phases: (rel 0..8) x (k-half 0,1).
// Block's CSR slice (offsets + edge indices) staged in LDS (contiguous by construction).
template<int OUTF32>
__global__ __launch_bounds__(256, 4) void layer_kernel(
    const unsigned short* __restrict__ h,      // [NN][128] bf16 (read-only)
    const int* __restrict__ off8, const int* __restrict__ eidx,
    const unsigned short* __restrict__ WTl,    // this layer: [9][128][128] bf16 [o][d]
    const float* __restrict__ bias,
    void* __restrict__ out)                    // [NN][128] bf16 or f32
{
  __shared__ __align__(16) char ldsW[2][DD * 64 * 2];   // 2 x 16 KB, XOR-swizzled
  __shared__ int ldsO[64 * NR + 1];                     // block's offset slice (2 KB)
  __shared__ int ldsE[CAPE];                            // block's edge slice  (4 KB)

  const int tid = threadIdx.x;
  const int rowBase = blockIdx.x * 64;
  const int lane = tid & 63;
  const int w = tid >> 6;            // 0..3
  const int c = lane & 15;           // node selector
  const int g = lane >> 4;           // k group
  const int n = rowBase + w * 16 + c;
  const int nld = (n < NN) ? n : (NN - 1);
  const int lnode = nld - rowBase;   // 0..63 (valid: last block clamps within range)

  // ---- stage CSR slice: offsets then contiguous eidx run ----
  const int nNodes = (NN - rowBase < 64) ? (NN - rowBase) : 64;
  const int onum = nNodes * NR + 1;
  for (int i = tid; i < onum; i += 256) ldsO[i] = off8[rowBase * NR + i];
  __syncthreads();
  const int blockBeg = ldsO[0];
  const int blockCnt = ldsO[onum - 1] - blockBeg;
  const int stCnt = (blockCnt < CAPE) ? blockCnt : CAPE;
  for (int i = tid; i < stCnt; i += 256) ldsE[i] = eidx[blockBeg + i];

  // staging geometry for W: 1024 chunks of 16B per half; thread owns 4.
  int dstB[4], srcRel[4];
#pragma unroll
  for (int j = 0; j < 4; ++j) {
    const int i = tid + j * 256;     // 0..1023
    const int o = i >> 3, slot = i & 7;
    dstB[j] = ((o << 7) | (slot << 4)) ^ ((o & 7) << 4);
    srcRel[j] = o * DD + slot * 8;
  }

  // prologue: stage W[0] half0 into buf0 (issue loads before barrier-wait on ldsE)
  uint4 wreg[4];
#pragma unroll
  for (int j = 0; j < 4; ++j)
    wreg[j] = *reinterpret_cast<const uint4*>(WTl + srcRel[j]);
#pragma unroll
  for (int j = 0; j < 4; ++j)
    *reinterpret_cast<uint4*>(ldsW[0] + dstB[j]) = wreg[j];
  __syncthreads();                   // ldsE + ldsW[0] ready

  // gather relation 0
  bf16x8 fA[4], fB[4];
  gather_frag_lds(h, eidx, ldsE, blockBeg, ldsO[lnode * NR], ldsO[lnode * NR + 1], g, fA);

  f32x4 acc[8];
#pragma unroll
  for (int t = 0; t < 8; ++t) acc[t] = (f32x4){0.f, 0.f, 0.f, 0.f};

  // phase P: r=P>>1, hf=P&1; reads buf[P&1]; stages phase P+1 into buf[(P+1)&1];
  // gathers relation r+1 on even phases.
#define PH(P, CUR, NXT)                                                               \
  {                                                                                   \
    __syncthreads();                                                                  \
    if ((P) < 17) {                                                                   \
      const unsigned short* wsrc = WTl                                                \
          + (size_t)(((P) + 1) >> 1) * DD * DD + (((P) + 1) & 1) * 64;                \
      _Pragma("unroll")                                                               \
      for (int j = 0; j < 4; ++j)                                                     \
        wreg[j] = *reinterpret_cast<const uint4*>(wsrc + srcRel[j]);                  \
    }                                                                                 \
    int gb = 0, ge = 0;                                                               \
    if (((P) & 1) == 0 && ((P) >> 1) + 1 < NR) {                                      \
      const int lo = lnode * NR + ((P) >> 1) + 1;                                     \
      gb = ldsO[lo]; ge = ldsO[lo + 1];                                               \
    }                                                                                 \
    _Pragma("unroll")                                                                 \
    for (int kl = 0; kl < 2; ++kl) {                                                  \
      _Pragma("unroll")                                                               \
      for (int t = 0; t < 8; ++t) {                                                   \
        const int addr = (((t * 16 + c) << 7) + ((kl * 4 + g) << 4)) ^ ((c & 7) << 4); \
        bf16x8 a = *reinterpret_cast<const bf16x8*>(ldsW[(P) & 1] + addr);            \
        acc[t] = __builtin_amdgcn_mfma_f32_16x16x32_bf16(                             \
            a, CUR[((P) & 1) * 2 + kl], acc[t], 0, 0, 0);                             \
      }                                                                               \
    }                                                                                 \
    if (((P) & 1) == 0) {                                                             \
      if (((P) >> 1) + 1 < NR) {                                                      \
        gather_frag_lds(h, eidx, ldsE, blockBeg, gb, ge, g, NXT);                     \
      } else if (((P) >> 1) + 1 == NR) {                                              \
        _Pragma("unroll")                                                             \
        for (int ks = 0; ks < 4; ++ks)                                                \
          NXT[ks] = *reinterpret_cast<const bf16x8*>(                                 \
              h + (size_t)nld * DD + ks * 32 + g * 8);                                \
      }                                                                               \
    }                                                                                 \
    if ((P) < 17) {                                                                   \
      _Pragma("unroll")                                                               \
      for (int j = 0; j < 4; ++j)                                                     \
        *reinterpret_cast<uint4*>(ldsW[((P) + 1) & 1] + dstB[j]) = wreg[j];           \
    }                                                                                 \
  }

  PH(0, fA, fB)  PH(1, fA, fB)
  PH(2, fB, fA)  PH(3, fB, fA)
  PH(4, fA, fB)  PH(5, fA, fB)
  PH(6, fB, fA)  PH(7, fB, fA)
  PH(8, fA, fB)  PH(9, fA, fB)
  PH(10, fB, fA) PH(11, fB, fA)
  PH(12, fA, fB) PH(13, fA, fB)
  PH(14, fB, fA) PH(15, fB, fA)
  PH(16, fA, fB) PH(17, fA, fB)
#undef PH

  if (n >= NN) return;
  if (OUTF32) {
    float* dst = (float*)out + (size_t)n * DD;
#pragma unroll
    for (int t = 0; t < 8; ++t) {
      const int o0 = t * 16 + g * 4;
      const float4 bv = *reinterpret_cast<const float4*>(bias + o0);
      float4 o;
      o.x = acc[t][0] + bv.x; o.y = acc[t][1] + bv.y;
      o.z = acc[t][2] + bv.z; o.w = acc[t][3] + bv.w;
      *reinterpret_cast<float4*>(dst + o0) = o;
    }
  } else {
    unsigned short* dst = (unsigned short*)out + (size_t)n * DD;
#pragma unroll
    for (int t = 0; t < 8; ++t) {
      const int o0 = t * 16 + g * 4;
      const float4 bv = *reinterpret_cast<const float4*>(bias + o0);
      uint2 q;
      q.x = pk2(acc[t][0] + bv.x, acc[t][1] + bv.y);
      q.y = pk2(acc[t][2] + bv.z, acc[t][3] + bv.w);
      *reinterpret_cast<uint2*>(dst + o0) = q;
    }
  }
}

extern "C" void kernel_launch(void* const* d_in, const int* in_sizes, int n_in,
                              void* d_out, int out_size, void* d_ws, size_t ws_size,
                              hipStream_t stream) {
  const int*   node_ids = (const int*)d_in[0];
  const int*   src   = (const int*)d_in[1];
  const int*   dst   = (const int*)d_in[2];
  const int*   etype = (const int*)d_in[3];
  const float* emb   = (const float*)d_in[4];
  const float* W1    = (const float*)d_in[5];
  const float* Ws1   = (const float*)d_in[6];
  const float* b1    = (const float*)d_in[7];
  const float* W2    = (const float*)d_in[8];
  const float* Ws2   = (const float*)d_in[9];
  const float* b2    = (const float*)d_in[10];

  // ws layout (~35 MB):
  //   h0     bf16 [NN*DD]       12.8 MB
  //   h1     bf16 [NN*DD]       12.8 MB
  //   WT     bf16 [18*DD*DD]     0.59 MB
  //   off8   i32  [NB+1]         1.6 MB
  //   deg8   i32  [NB]           1.6 MB
  //   eidx   i32  [NE]           2.4 MB
  //   bsum/bbase i32 [NCHUNK8]
  char* p = (char*)d_ws;
  unsigned short* h0 = (unsigned short*)p;  p += (size_t)NN * DD * 2;
  unsigned short* h1 = (unsigned short*)p;  p += (size_t)NN * DD * 2;
  unsigned short* WT = (unsigned short*)p;  p += (size_t)18 * DD * DD * 2;
  int* off8          = (int*)p;             p += (size_t)(NB + 1) * 4;
  int* deg8          = (int*)p;             p += (size_t)NB * 4;
  int* eidx          = (int*)p;             p += (size_t)NE * 4;
  int* bsum          = (int*)p;             p += (size_t)NCHUNK8 * 4;
  int* bbase         = (int*)p;

  const int eb = (NE + 255) / 256;
  const int tb = (NN + 63) / 64;     // 782

  // weight convert + h0 convert + CSR build over (dst,rel)
  convw_kernel<<<dim3(DD, 18), 128, 0, stream>>>(W1, Ws1, W2, Ws2, WT);
  convh_kernel<<<(NN * 16) / 256, 256, 0, stream>>>(emb, node_ids, h0);
  hipMemsetAsync(deg8, 0, (size_t)NB * 4, stream);
  hist_kernel<<<eb, 256, 0, stream>>>(dst, etype, deg8);
  bsum_kernel<<<NCHUNK8, 256, 0, stream>>>(deg8, bsum);
  bscan_kernel<<<1, 256, 0, stream>>>(bsum, bbase);
  expand_kernel<<<NCHUNK8, 256, 0, stream>>>(deg8, bbase, off8);
  fill_kernel<<<eb, 256, 0, stream>>>(src, dst, etype, deg8, eidx);

  // fused layers (no s materialization)
  layer_kernel<0><<<tb, 256, 0, stream>>>(h0, off8, eidx, WT, b1, h1);
  layer_kernel<1><<<tb, 256, 0, stream>>>(h1, off8, eidx, WT + (size_t)9 * DD * DD, b2, (float*)d_out);
}